// Round 3
// baseline (274.514 us; speedup 1.0000x reference)
//
#include <hip/hip_runtime.h>
#include <hip/hip_bf16.h>
#include <stdint.h>

// VectorQuantizer on MI355X (gfx950) — round 3 (round-2 structure, loss fix)
// inputs: x [64,256,32,32] fp32 (NCHW), codebook [1024,256] fp32
// outputs: q_st [64,256,32,32] fp32 (codebook[argmin] scattered back), loss scalar
//
// Flipped GEMM: D[m=code][n=hw] via mfma_f32_32x32x16_bf16.
//  - x is the B operand: n=hw is the contiguous NCHW axis -> no transpose, no
//    LDS staging; loaded once per wave, held in 128 VGPRs.
//  - codebook is the A operand, pre-swizzled into exact fragment order so the
//    K-loop A-load is one coalesced dwordx4 per lane.
//  - norms folded into acc init: acc0 = -0.5*||c||^2  =>  argmin dist ==
//    argmax acc, minscore = -2*acc. In-lane argmax (C/D col = lane&31 = hw).
//  - wave pair splits the 1024 codes (512 each) -> halves codebook traffic.
//  - LOSS FIX (r2 bug): both waves compute identical ||x||^2 partials; sum
//    wave 0's only (its 64 lanes cover every (row, d-half) exactly once).

#define DIM 256

typedef __attribute__((ext_vector_type(8)))  short bf16x8_t;   // MFMA A/B frag (4 VGPRs)
typedef __attribute__((ext_vector_type(4)))  float f32x4_t;
typedef __attribute__((ext_vector_type(16))) float f32x16_t;   // 32x32 C/D frag

__device__ __forceinline__ uint32_t f2bf(float f) {
    union { float f; uint32_t u; } v; v.f = f;
    uint32_t r = v.u + 0x7FFFu + ((v.u >> 16) & 1u);   // RNE
    return r >> 16;
}

// ---- prep A: swizzle codebook fp32 -> bf16 in MFMA A-frag order ----
// entry e = (mt*16 + ks)*64 + lane  holds  cb[mt*32 + (lane&31)][ks*16 + (lane>>5)*8 + j]
__global__ __launch_bounds__(256) void vq_prep_sw(const float* __restrict__ cb,
                                                  bf16x8_t* __restrict__ cbsw) {
    const int e    = blockIdx.x * 256 + threadIdx.x;    // 0..32767
    const int lane = e & 63;
    const int ks   = (e >> 6) & 15;
    const int mt   = e >> 10;
    const int code = mt * 32 + (lane & 31);
    const int d0   = ks * 16 + (lane >> 5) * 8;
    const f32x4_t* p = (const f32x4_t*)(cb + code * DIM + d0);
    const f32x4_t v0 = p[0], v1 = p[1];
    union { bf16x8_t v; uint32_t u[4]; } f;
    f.u[0] = f2bf(v0.x) | (f2bf(v0.y) << 16);
    f.u[1] = f2bf(v0.z) | (f2bf(v0.w) << 16);
    f.u[2] = f2bf(v1.x) | (f2bf(v1.y) << 16);
    f.u[3] = f2bf(v1.z) | (f2bf(v1.w) << 16);
    cbsw[e] = f.v;
}

// ---- prep B: nh_ord[mt*32 + half*16 + r] = -0.5*||cb[code]||^2 in C/D reg order
// code row-in-tile = (r&3) + 4*half + 8*(r>>2)
__global__ __launch_bounds__(256) void vq_prep_nh(const float* __restrict__ cb,
                                                  float* __restrict__ nh_ord) {
    const int code = blockIdx.x * 4 + (threadIdx.x >> 6);
    const int lane = threadIdx.x & 63;
    const f32x4_t v = ((const f32x4_t*)(cb + code * DIM))[lane];
    float sq = v.x * v.x + v.y * v.y + v.z * v.z + v.w * v.w;
    #pragma unroll
    for (int m = 32; m; m >>= 1) sq += __shfl_xor(sq, m, 64);
    if (lane == 0) {
        const int mt = code >> 5, rw = code & 31;
        const int half = (rw >> 2) & 1;
        const int r    = (rw & 3) | ((rw >> 3) << 2);
        nh_ord[mt * 32 + half * 16 + r] = -0.5f * sq;
    }
}

// ---- main kernel: 1024 blocks x 128 threads; block = 64 hw rows, wave pair splits codes
__global__ __launch_bounds__(128, 2) void vq_main(const float* __restrict__ x,
                                                  const float* __restrict__ cb,
                                                  const bf16x8_t* __restrict__ cbsw,
                                                  const float* __restrict__ nh_ord,
                                                  float* __restrict__ out,
                                                  float* __restrict__ loss_accum) {
    __shared__ float smin[2][64];
    __shared__ int   sidx[2][64];
    __shared__ float sxsq[64];
    __shared__ int   sfin[64];

    const int t    = threadIdx.x;
    const int w    = t >> 6;          // wave 0/1 = code halves [0,512) / [512,1024)
    const int lane = t & 63;
    const int col  = lane & 31;       // = hw within n-tile
    const int half = lane >> 5;       // k-half
    const int n0   = blockIdx.x * 64;
    const int batch = n0 >> 10;
    const int hw0   = n0 & 1023;
    const float* xb = x + (size_t)batch * (DIM * 1024) + hw0;

    // ---- load x B-frags (held in registers through the whole K-loop) + fp32 ||x||^2
    bf16x8_t xf[2][16];
    float sq[2] = {0.f, 0.f};
    #pragma unroll
    for (int nt = 0; nt < 2; ++nt) {
        const float* xp = xb + nt * 32 + col;
        #pragma unroll
        for (int ks = 0; ks < 16; ++ks) {
            const int d0 = ks * 16 + half * 8;
            union { bf16x8_t v; uint32_t u[4]; } f;
            #pragma unroll
            for (int j = 0; j < 4; ++j) {
                const float a0 = xp[(size_t)(d0 + 2 * j) * 1024];
                const float a1 = xp[(size_t)(d0 + 2 * j + 1) * 1024];
                sq[nt] += a0 * a0 + a1 * a1;
                f.u[j] = f2bf(a0) | (f2bf(a1) << 16);
            }
            xf[nt][ks] = f.v;
        }
    }

    // ---- K-loop: this wave's 16 m-tiles (512 codes); argmax of (dot - 0.5*||c||^2)
    float best0 = -3.0e38f, best1 = -3.0e38f;
    int   bi0 = 0, bi1 = 0;
    const int mt0 = w * 16;
    for (int i = 0; i < 16; ++i) {
        const int mt = mt0 + i;
        const f32x4_t* nhp = (const f32x4_t*)(nh_ord + mt * 32 + half * 16);
        const f32x4_t h0 = nhp[0], h1 = nhp[1], h2 = nhp[2], h3 = nhp[3];
        f32x16_t acc0, acc1;
        #pragma unroll
        for (int r = 0; r < 4; ++r) {
            acc0[r] = h0[r]; acc0[4 + r] = h1[r]; acc0[8 + r] = h2[r]; acc0[12 + r] = h3[r];
        }
        acc1 = acc0;
        const bf16x8_t* ap = cbsw + mt * (16 * 64) + lane;
        #pragma unroll
        for (int ks = 0; ks < 16; ++ks) {
            const bf16x8_t a = ap[ks * 64];
            acc0 = __builtin_amdgcn_mfma_f32_32x32x16_bf16(a, xf[0][ks], acc0, 0, 0, 0);
            acc1 = __builtin_amdgcn_mfma_f32_32x32x16_bf16(a, xf[1][ks], acc1, 0, 0, 0);
        }
        #pragma unroll
        for (int r = 0; r < 16; ++r) {
            const int code = mt * 32 + half * 4 + ((r & 3) + 8 * (r >> 2));
            if (acc0[r] > best0) { best0 = acc0[r]; bi0 = code; }
            if (acc1[r] > best1) { best1 = acc1[r]; bi1 = code; }
        }
    }

    // ---- combine the two k-half lanes (same hw, disjoint code rows)
    {
        float ov = __shfl_xor(best0, 32); int oi = __shfl_xor(bi0, 32);
        if (ov > best0 || (ov == best0 && oi < bi0)) { best0 = ov; bi0 = oi; }
        ov = __shfl_xor(best1, 32); oi = __shfl_xor(bi1, 32);
        if (ov > best1 || (ov == best1 && oi < bi1)) { best1 = ov; bi1 = oi; }
    }
    if (lane < 32) {
        smin[w][lane]      = best0; sidx[w][lane]      = bi0;
        smin[w][32 + lane] = best1; sidx[w][32 + lane] = bi1;
    }
    if (w == 0) sxsq[lane] = sq[0] + sq[1];   // wave 0 only: covers every (row, d-half) once
    __syncthreads();

    // ---- wave 0 finalizes: combine code halves, loss partial, publish indices
    if (w == 0) {
        float b0 = smin[0][lane]; int i0 = sidx[0][lane];
        const float b1 = smin[1][lane]; const int i1 = sidx[1][lane];
        if (b1 > b0) { b0 = b1; i0 = i1; }
        sfin[lane] = i0;
        float ls = -2.f * b0 + sxsq[lane];
        #pragma unroll
        for (int m = 32; m; m >>= 1) ls += __shfl_xor(ls, m);
        if (lane == 0) atomicAdd(loss_accum, ls);
    }
    __syncthreads();

    // ---- epilogue: gather fp32 codebook rows, dwordx4 stores along hw
    {
        const int q  = t & 15;     // hw quad: hw = 4q..4q+3
        const int dg = t >> 4;     // 0..7 -> d in [dg*32, dg*32+32)
        const int c0 = sfin[4 * q + 0], c1 = sfin[4 * q + 1];
        const int c2 = sfin[4 * q + 2], c3 = sfin[4 * q + 3];
        const float* r0 = cb + c0 * DIM;
        const float* r1 = cb + c1 * DIM;
        const float* r2 = cb + c2 * DIM;
        const float* r3 = cb + c3 * DIM;
        float* ob = out + (size_t)batch * (DIM * 1024) + hw0 + 4 * q;
        #pragma unroll 8
        for (int j = 0; j < 32; ++j) {
            const int d = dg * 32 + j;
            f32x4_t v; v.x = r0[d]; v.y = r1[d]; v.z = r2[d]; v.w = r3[d];
            *(f32x4_t*)(ob + (size_t)d * 1024) = v;
        }
    }
}

// ---- finalize loss ----
__global__ void vq_final(const float* __restrict__ loss_accum, float* __restrict__ out_loss) {
    *out_loss = 1.25f * (*loss_accum) / 16777216.f;
}

extern "C" void kernel_launch(void* const* d_in, const int* in_sizes, int n_in,
                              void* d_out, int out_size, void* d_ws, size_t ws_size,
                              hipStream_t stream) {
    const float* x  = (const float*)d_in[0];   // [64,256,32,32]
    const float* cb = (const float*)d_in[1];   // [1024,256]
    float* out = (float*)d_out;                // 16777216 + 1

    char* ws = (char*)d_ws;
    float*     loss_accum = (float*)ws;                        // 4 B
    bf16x8_t*  cbsw       = (bf16x8_t*)(ws + 1024);            // 512 KB
    float*     nh_ord     = (float*)(ws + 1024 + 512 * 1024);  // 4 KB

    hipMemsetAsync(loss_accum, 0, sizeof(float), stream);
    vq_prep_sw<<<dim3(128), dim3(256), 0, stream>>>(cb, cbsw);
    vq_prep_nh<<<dim3(256), dim3(256), 0, stream>>>(cb, nh_ord);
    vq_main<<<dim3(1024), dim3(128), 0, stream>>>(x, cb, cbsw, nh_ord, out, loss_accum);
    vq_final<<<dim3(1), dim3(1), 0, stream>>>(loss_accum, out + 16777216);
}

// Round 4
// 233.993 us; speedup vs baseline: 1.1732x; 1.1732x over previous
//
#include <hip/hip_runtime.h>
#include <hip/hip_bf16.h>
#include <stdint.h>

// VectorQuantizer on MI355X (gfx950) — round 4
// inputs: x [64,256,32,32] fp32 (NCHW), codebook [1024,256] fp32
// outputs: q_st [64,256,32,32] fp32 (codebook[argmin] scattered back), loss scalar
//
// Flipped GEMM D[m=code][n=hw] via mfma_f32_32x32x16_bf16, x as B operand
// (hw-contiguous -> no transpose), codebook pre-swizzled to A-frag order.
// R4 changes vs R3 (which spilled ~700 B/thread: WRITE_SIZE 157 MB vs 64):
//  - wave = 1 n-tile (32 rows) x 1 code-half (512 codes): xf[16]=64 VGPRs,
//    one f32x16 acc=16 -> no spill under __launch_bounds__(256,4).
//  - block = 256 threads (2 n-tiles x 2 code-halves), 64 rows; 1024 blocks
//    -> 4096 waves = 4/SIMD (2x occupancy of R3).
//  - prep kernels merged (wave-per-code: swizzle + norm in one pass).

#define DIM 256

typedef __attribute__((ext_vector_type(8)))  short bf16x8_t;   // MFMA A/B frag (4 VGPRs)
typedef __attribute__((ext_vector_type(4)))  float f32x4_t;
typedef __attribute__((ext_vector_type(16))) float f32x16_t;   // 32x32 C/D frag

__device__ __forceinline__ uint32_t f2bf(float f) {
    union { float f; uint32_t u; } v; v.f = f;
    uint32_t r = v.u + 0x7FFFu + ((v.u >> 16) & 1u);   // RNE
    return r >> 16;
}

// ---- prep: one wave per code. Emits (a) bf16 codebook in exact MFMA A-frag
// order: entry e=(mt*16+ks)*64+lane2 holds cb[mt*32+(lane2&31)][ks*16+(lane2>>5)*8+j],
// and (b) -0.5*||c||^2 in C/D-register order (nh_ord[mt*32 + half*16 + r]).
__global__ __launch_bounds__(256) void vq_prep(const float* __restrict__ cb,
                                               char* __restrict__ cbsw,
                                               float* __restrict__ nh_ord) {
    const int code = blockIdx.x * 4 + (threadIdx.x >> 6);
    const int l    = threadIdx.x & 63;               // holds d = 4l..4l+3
    const f32x4_t v = ((const f32x4_t*)(cb + code * DIM))[l];
    float sq = v.x * v.x + v.y * v.y + v.z * v.z + v.w * v.w;

    const int mt = code >> 5;
    const int ks = l >> 2;               // d/16
    const int hl = (l >> 1) & 1;         // (d%16)/8
    const uint32_t ebyte = (uint32_t)(((mt * 16 + ks) * 64 + (code & 31) + 32 * hl) * 16
                                      + (l & 1) * 8);
    uint2 o;
    o.x = f2bf(v.x) | (f2bf(v.y) << 16);
    o.y = f2bf(v.z) | (f2bf(v.w) << 16);
    *(uint2*)(cbsw + ebyte) = o;

    #pragma unroll
    for (int m = 32; m; m >>= 1) sq += __shfl_xor(sq, m);
    if (l == 0) {
        const int rw = code & 31;
        const int h4 = (rw >> 2) & 1;
        const int r  = (rw & 3) | ((rw >> 3) << 2);
        nh_ord[mt * 32 + h4 * 16 + r] = -0.5f * sq;
    }
}

// ---- main: 1024 blocks x 256 threads; block = 64 hw rows.
// wave w: n-tile nt=w&1 (rows nt*32..), code-half ch=w>>1 (codes ch*512..).
__global__ __launch_bounds__(256, 4) void vq_main(const float* __restrict__ x,
                                                  const float* __restrict__ cb,
                                                  const bf16x8_t* __restrict__ cbsw,
                                                  const float* __restrict__ nh_ord,
                                                  float* __restrict__ out,
                                                  float* __restrict__ loss_accum) {
    __shared__ float smin[2][64];
    __shared__ int   sidx[2][64];
    __shared__ float sxsq[2];
    __shared__ int   sfin[64];

    const int t    = threadIdx.x;
    const int w    = t >> 6;
    const int lane = t & 63;
    const int nt   = w & 1;
    const int ch   = w >> 1;
    const int col  = lane & 31;       // hw within n-tile
    const int half = lane >> 5;       // k-half
    const int n0   = blockIdx.x * 64;
    const int batch = n0 >> 10;
    const int hw0   = n0 & 1023;
    const float* xp = x + (size_t)batch * (DIM * 1024) + hw0 + nt * 32 + col;

    // ---- x B-frags in registers (64 VGPRs) + fp32 ||x||^2 partial
    bf16x8_t xf[16];
    float sq = 0.f;
    #pragma unroll
    for (int ks = 0; ks < 16; ++ks) {
        const int d0 = ks * 16 + half * 8;
        union { bf16x8_t v; uint32_t u[4]; } f;
        #pragma unroll
        for (int j = 0; j < 4; ++j) {
            const float a0 = xp[(size_t)(d0 + 2 * j) * 1024];
            const float a1 = xp[(size_t)(d0 + 2 * j + 1) * 1024];
            sq += a0 * a0 + a1 * a1;
            f.u[j] = f2bf(a0) | (f2bf(a1) << 16);
        }
        xf[ks] = f.v;
    }

    // ---- K-loop: 16 m-tiles (this wave's 512 codes); argmax(dot - 0.5*||c||^2)
    float best = -3.0e38f;
    int   bi = 0;
    for (int i = 0; i < 16; ++i) {
        const int mt = ch * 16 + i;
        const f32x4_t* nhp = (const f32x4_t*)(nh_ord + mt * 32 + half * 16);
        const f32x4_t h0 = nhp[0], h1 = nhp[1], h2 = nhp[2], h3 = nhp[3];
        f32x16_t acc;
        #pragma unroll
        for (int r = 0; r < 4; ++r) {
            acc[r] = h0[r]; acc[4 + r] = h1[r]; acc[8 + r] = h2[r]; acc[12 + r] = h3[r];
        }
        const bf16x8_t* ap = cbsw + mt * (16 * 64) + lane;
        #pragma unroll
        for (int ks = 0; ks < 16; ++ks)
            acc = __builtin_amdgcn_mfma_f32_32x32x16_bf16(ap[ks * 64], xf[ks], acc, 0, 0, 0);
        #pragma unroll
        for (int r = 0; r < 16; ++r) {
            const int code = mt * 32 + half * 4 + ((r & 3) + 8 * (r >> 2));
            if (acc[r] > best) { best = acc[r]; bi = code; }
        }
    }

    // ---- combine the two k-half lanes (same hw row, disjoint code subsets)
    {
        const float ov = __shfl_xor(best, 32);
        const int   oi = __shfl_xor(bi, 32);
        if (ov > best || (ov == best && oi < bi)) { best = ov; bi = oi; }
    }
    if (lane < 32) {
        smin[ch][nt * 32 + lane] = best;
        sidx[ch][nt * 32 + lane] = bi;
    }
    // ---- loss ||x||^2 partial: ch==0 waves only (cover all 64 rows, all d)
    if (ch == 0) {
        float s = sq;
        #pragma unroll
        for (int m = 32; m; m >>= 1) s += __shfl_xor(s, m);
        if (lane == 0) sxsq[nt] = s;
    }
    __syncthreads();

    // ---- wave 0: combine code halves per row, loss partial, publish indices
    if (w == 0) {
        float b0 = smin[0][lane]; int i0 = sidx[0][lane];
        const float b1 = smin[1][lane]; const int i1 = sidx[1][lane];
        if (b1 > b0) { b0 = b1; i0 = i1; }   // strict: ch0 codes win ties
        sfin[lane] = i0;
        float ls = -2.f * b0;
        #pragma unroll
        for (int m = 32; m; m >>= 1) ls += __shfl_xor(ls, m);
        if (lane == 0) atomicAdd(loss_accum, ls + sxsq[0] + sxsq[1]);
    }
    __syncthreads();

    // ---- epilogue: gather fp32 codebook rows, dwordx4 stores along hw
    {
        const int q  = t & 15;     // rows 4q..4q+3
        const int dg = t >> 4;     // 0..15 -> d in [dg*16, dg*16+16)
        const int c0 = sfin[4 * q + 0], c1 = sfin[4 * q + 1];
        const int c2 = sfin[4 * q + 2], c3 = sfin[4 * q + 3];
        const float* r0 = cb + c0 * DIM;
        const float* r1 = cb + c1 * DIM;
        const float* r2 = cb + c2 * DIM;
        const float* r3 = cb + c3 * DIM;
        float* ob = out + (size_t)batch * (DIM * 1024) + hw0 + 4 * q;
        #pragma unroll 4
        for (int j = 0; j < 16; ++j) {
            const int d = dg * 16 + j;
            f32x4_t v; v.x = r0[d]; v.y = r1[d]; v.z = r2[d]; v.w = r3[d];
            *(f32x4_t*)(ob + (size_t)d * 1024) = v;
        }
    }
}

// ---- finalize loss ----
__global__ void vq_final(const float* __restrict__ loss_accum, float* __restrict__ out_loss) {
    *out_loss = 1.25f * (*loss_accum) / 16777216.f;
}

extern "C" void kernel_launch(void* const* d_in, const int* in_sizes, int n_in,
                              void* d_out, int out_size, void* d_ws, size_t ws_size,
                              hipStream_t stream) {
    const float* x  = (const float*)d_in[0];   // [64,256,32,32]
    const float* cb = (const float*)d_in[1];   // [1024,256]
    float* out = (float*)d_out;                // 16777216 + 1

    char* ws = (char*)d_ws;
    float* loss_accum = (float*)ws;                        // 4 B
    char*  cbsw       = ws + 1024;                         // 512 KB, A-frag order
    float* nh_ord     = (float*)(ws + 1024 + 512 * 1024);  // 4 KB

    hipMemsetAsync(loss_accum, 0, sizeof(float), stream);
    vq_prep<<<dim3(256), dim3(256), 0, stream>>>(cb, ws + 1024, nh_ord);
    vq_main<<<dim3(1024), dim3(256), 0, stream>>>(x, cb, (const bf16x8_t*)cbsw, nh_ord,
                                                  out, loss_accum);
    vq_final<<<dim3(1), dim3(1), 0, stream>>>(loss_accum, out + 16777216);
}

// Round 5
// 191.422 us; speedup vs baseline: 1.4341x; 1.2224x over previous
//
#include <hip/hip_runtime.h>
#include <hip/hip_bf16.h>
#include <stdint.h>

// VectorQuantizer on MI355X (gfx950) — round 5
// inputs: x [64,256,32,32] fp32 (NCHW), codebook [1024,256] fp32
// outputs: q_st [64,256,32,32] fp32 (codebook[argmin] scattered back), loss scalar
//
// Flipped GEMM D[m=code][n=hw] via mfma_f32_32x32x16_bf16.
// R5 vs R4: x B-fragments move from registers (which spilled: WRITE_SIZE
// 162 MB vs 64 MB of output, ~94 MB of scratch writeback) into LDS, staged
// once in exact fragment order. K-loop = global dwordx4 A-stream (L2-resident
// swizzled codebook) + conflict-free ds_read_b128 B-frags + MFMA. Per-wave
// state ~40 VGPR + 16 AGPR -> no spill possible. LDS 33 KB -> 4 blocks/CU.

#define DIM 256

typedef __attribute__((ext_vector_type(8)))  short bf16x8_t;   // MFMA A/B frag (4 VGPRs)
typedef __attribute__((ext_vector_type(4)))  float f32x4_t;
typedef __attribute__((ext_vector_type(16))) float f32x16_t;   // 32x32 C/D frag

__device__ __forceinline__ uint32_t f2bf(float f) {
    union { float f; uint32_t u; } v; v.f = f;
    uint32_t r = v.u + 0x7FFFu + ((v.u >> 16) & 1u);   // RNE
    return r >> 16;
}

// ---- prep: one wave per code. Emits (a) bf16 codebook in exact MFMA A-frag
// order: entry e=(mt*16+ks)*64+lane2 holds cb[mt*32+(lane2&31)][ks*16+(lane2>>5)*8+j],
// and (b) -0.5*||c||^2 in C/D-register order (nh_ord[mt*32 + half*16 + r]).
__global__ __launch_bounds__(256) void vq_prep(const float* __restrict__ cb,
                                               char* __restrict__ cbsw,
                                               float* __restrict__ nh_ord) {
    const int code = blockIdx.x * 4 + (threadIdx.x >> 6);
    const int l    = threadIdx.x & 63;               // holds d = 4l..4l+3
    const f32x4_t v = ((const f32x4_t*)(cb + code * DIM))[l];
    float sq = v.x * v.x + v.y * v.y + v.z * v.z + v.w * v.w;

    const int mt = code >> 5;
    const int ks = l >> 2;               // d/16
    const int hl = (l >> 1) & 1;         // (d%16)/8
    const uint32_t ebyte = (uint32_t)(((mt * 16 + ks) * 64 + (code & 31) + 32 * hl) * 16
                                      + (l & 1) * 8);
    uint2 o;
    o.x = f2bf(v.x) | (f2bf(v.y) << 16);
    o.y = f2bf(v.z) | (f2bf(v.w) << 16);
    *(uint2*)(cbsw + ebyte) = o;

    #pragma unroll
    for (int m = 32; m; m >>= 1) sq += __shfl_xor(sq, m);
    if (l == 0) {
        const int rw = code & 31;
        const int h4 = (rw >> 2) & 1;
        const int r  = (rw & 3) | ((rw >> 3) << 2);
        nh_ord[mt * 32 + h4 * 16 + r] = -0.5f * sq;
    }
}

// ---- main: 1024 blocks x 256 threads; block = 64 hw rows.
// LDS xt entry E=(ks*2+half)*64+row holds x[row][ks*16+half*8 .. +7] as 8 bf16 (16 B).
// Wave w: n-tile nt=w&1 (rows nt*32..), code-half ch=w>>1 (codes ch*512..).
__global__ __launch_bounds__(256) void vq_main(const float* __restrict__ x,
                                               const float* __restrict__ cb,
                                               const bf16x8_t* __restrict__ cbsw,
                                               const float* __restrict__ nh_ord,
                                               float* __restrict__ out,
                                               float* __restrict__ loss_accum) {
    __shared__ uint32_t xt[16 * 2 * 64 * 4];   // 32 KB, B-frag order
    __shared__ float smin[2][64];
    __shared__ int   sidx[2][64];
    __shared__ float sxsq[4];
    __shared__ int   sfin[64];

    const int t     = threadIdx.x;
    const int w     = t >> 6;
    const int lane  = t & 63;
    const int n0    = blockIdx.x * 64;
    const int batch = n0 >> 10;
    const int hw0   = n0 & 1023;

    // ---- stage x -> LDS in fragment order (conflict-free b128 writes) + ||x||^2
    {
        const int col = t & 63;          // hw row within block
        const int oct = t >> 6;          // 0..3: d-octet selector
        const float* xp = x + (size_t)batch * (DIM * 1024) + hw0 + col;
        float sq = 0.f;
        #pragma unroll
        for (int i = 0; i < 8; ++i) {
            const int d0 = oct * 8 + i * 32;     // 8 consecutive d, one LDS entry
            float a[8];
            #pragma unroll
            for (int j = 0; j < 8; ++j) {
                a[j] = xp[(size_t)(d0 + j) * 1024];
                sq += a[j] * a[j];
            }
            uint4 pk;
            pk.x = f2bf(a[0]) | (f2bf(a[1]) << 16);
            pk.y = f2bf(a[2]) | (f2bf(a[3]) << 16);
            pk.z = f2bf(a[4]) | (f2bf(a[5]) << 16);
            pk.w = f2bf(a[6]) | (f2bf(a[7]) << 16);
            const int ks   = d0 >> 4;
            const int half = (d0 >> 3) & 1;
            *(uint4*)&xt[(ks * 512) + (half * 256) + col * 4] = pk;
        }
        // wave-level ||x||^2 partial (all 256 threads cover every (row,d) once)
        #pragma unroll
        for (int m = 32; m; m >>= 1) sq += __shfl_xor(sq, m);
        if (lane == 0) sxsq[w] = sq;
    }
    __syncthreads();

    // ---- K-loop: wave's 512 codes (16 m-tiles); argmax(dot - 0.5*||c||^2)
    const int nt   = w & 1;
    const int ch   = w >> 1;
    const int half = lane >> 5;
    const int col  = lane & 31;
    const uint32_t* xbase = xt + half * 256 + (nt * 32 + col) * 4;

    float best = -3.0e38f;
    int   bi = 0;
    for (int i = 0; i < 16; ++i) {
        const int mt = ch * 16 + i;
        const f32x4_t* nhp = (const f32x4_t*)(nh_ord + mt * 32 + half * 16);
        const f32x4_t h0 = nhp[0], h1 = nhp[1], h2 = nhp[2], h3 = nhp[3];
        f32x16_t acc;
        #pragma unroll
        for (int r = 0; r < 4; ++r) {
            acc[r] = h0[r]; acc[4 + r] = h1[r]; acc[8 + r] = h2[r]; acc[12 + r] = h3[r];
        }
        const bf16x8_t* ap = cbsw + mt * (16 * 64) + lane;
        #pragma unroll
        for (int ks = 0; ks < 16; ++ks) {
            const bf16x8_t b = *(const bf16x8_t*)(xbase + ks * 512);
            acc = __builtin_amdgcn_mfma_f32_32x32x16_bf16(ap[ks * 64], b, acc, 0, 0, 0);
        }
        #pragma unroll
        for (int r = 0; r < 16; ++r) {
            const int code = mt * 32 + half * 4 + ((r & 3) + 8 * (r >> 2));
            if (acc[r] > best) { best = acc[r]; bi = code; }
        }
    }

    // ---- combine the two k-half lanes (same hw row, disjoint code subsets)
    {
        const float ov = __shfl_xor(best, 32);
        const int   oi = __shfl_xor(bi, 32);
        if (ov > best || (ov == best && oi < bi)) { best = ov; bi = oi; }
    }
    if (lane < 32) {
        smin[ch][nt * 32 + lane] = best;
        sidx[ch][nt * 32 + lane] = bi;
    }
    __syncthreads();

    // ---- wave 0: combine code halves per row, loss partial, publish indices
    if (w == 0) {
        float b0 = smin[0][lane]; int i0 = sidx[0][lane];
        const float b1 = smin[1][lane]; const int i1 = sidx[1][lane];
        if (b1 > b0) { b0 = b1; i0 = i1; }
        sfin[lane] = i0;
        float ls = -2.f * b0;
        #pragma unroll
        for (int m = 32; m; m >>= 1) ls += __shfl_xor(ls, m);
        if (lane == 0)
            atomicAdd(loss_accum, ls + sxsq[0] + sxsq[1] + sxsq[2] + sxsq[3]);
    }
    __syncthreads();

    // ---- epilogue: gather fp32 codebook rows, dwordx4 stores along hw
    {
        const int q  = t & 15;     // rows 4q..4q+3
        const int dg = t >> 4;     // 0..15 -> d in [dg*16, dg*16+16)
        const int c0 = sfin[4 * q + 0], c1 = sfin[4 * q + 1];
        const int c2 = sfin[4 * q + 2], c3 = sfin[4 * q + 3];
        const float* r0 = cb + c0 * DIM;
        const float* r1 = cb + c1 * DIM;
        const float* r2 = cb + c2 * DIM;
        const float* r3 = cb + c3 * DIM;
        float* ob = out + (size_t)batch * (DIM * 1024) + hw0 + 4 * q;
        #pragma unroll 4
        for (int j = 0; j < 16; ++j) {
            const int d = dg * 16 + j;
            f32x4_t v; v.x = r0[d]; v.y = r1[d]; v.z = r2[d]; v.w = r3[d];
            *(f32x4_t*)(ob + (size_t)d * 1024) = v;
        }
    }
}

// ---- finalize loss ----
__global__ void vq_final(const float* __restrict__ loss_accum, float* __restrict__ out_loss) {
    *out_loss = 1.25f * (*loss_accum) / 16777216.f;
}

extern "C" void kernel_launch(void* const* d_in, const int* in_sizes, int n_in,
                              void* d_out, int out_size, void* d_ws, size_t ws_size,
                              hipStream_t stream) {
    const float* x  = (const float*)d_in[0];   // [64,256,32,32]
    const float* cb = (const float*)d_in[1];   // [1024,256]
    float* out = (float*)d_out;                // 16777216 + 1

    char* ws = (char*)d_ws;
    float* loss_accum = (float*)ws;                        // 4 B
    char*  cbsw       = ws + 1024;                         // 512 KB, A-frag order
    float* nh_ord     = (float*)(ws + 1024 + 512 * 1024);  // 4 KB

    hipMemsetAsync(loss_accum, 0, sizeof(float), stream);
    vq_prep<<<dim3(256), dim3(256), 0, stream>>>(cb, cbsw, nh_ord);
    vq_main<<<dim3(1024), dim3(256), 0, stream>>>(x, cb, (const bf16x8_t*)cbsw, nh_ord,
                                                  out, loss_accum);
    vq_final<<<dim3(1), dim3(1), 0, stream>>>(loss_accum, out + 16777216);
}

// Round 6
// 164.506 us; speedup vs baseline: 1.6687x; 1.1636x over previous
//
#include <hip/hip_runtime.h>
#include <hip/hip_bf16.h>
#include <stdint.h>

// VectorQuantizer on MI355X (gfx950) — round 6
// inputs: x [64,256,32,32] fp32 (NCHW), codebook [1024,256] fp32
// outputs: q_st [64,256,32,32] fp32 (codebook[argmin] scattered back), loss scalar
//
// Flipped GEMM D[m=code][n=hw] via mfma_f32_32x32x16_bf16. x staged once to
// LDS in B-frag order (R5, no-spill). R6: the A-stream (swizzled L2-resident
// codebook) is batch-prefetched 16 frags at a time into registers so the
// compiler drains vmcnt(15..0) interleaved with MFMAs instead of a naked
// vmcnt(0) per load (R5: VGPR=60, MfmaUtil 12%, ~200cyc L2 latency exposed
// per iteration). __launch_bounds__(256,3) caps regs at ~170: no spill cliff.

#define DIM 256

typedef __attribute__((ext_vector_type(8)))  short bf16x8_t;   // MFMA A/B frag (4 VGPRs)
typedef __attribute__((ext_vector_type(4)))  float f32x4_t;
typedef __attribute__((ext_vector_type(16))) float f32x16_t;   // 32x32 C/D frag

__device__ __forceinline__ uint32_t f2bf(float f) {
    union { float f; uint32_t u; } v; v.f = f;
    uint32_t r = v.u + 0x7FFFu + ((v.u >> 16) & 1u);   // RNE
    return r >> 16;
}

// ---- prep: one wave per code. Emits (a) bf16 codebook in exact MFMA A-frag
// order: entry e=(mt*16+ks)*64+lane2 holds cb[mt*32+(lane2&31)][ks*16+(lane2>>5)*8+j],
// and (b) -0.5*||c||^2 in C/D-register order (nh_ord[mt*32 + half*16 + r]).
__global__ __launch_bounds__(256) void vq_prep(const float* __restrict__ cb,
                                               char* __restrict__ cbsw,
                                               float* __restrict__ nh_ord) {
    const int code = blockIdx.x * 4 + (threadIdx.x >> 6);
    const int l    = threadIdx.x & 63;               // holds d = 4l..4l+3
    const f32x4_t v = ((const f32x4_t*)(cb + code * DIM))[l];
    float sq = v.x * v.x + v.y * v.y + v.z * v.z + v.w * v.w;

    const int mt = code >> 5;
    const int ks = l >> 2;               // d/16
    const int hl = (l >> 1) & 1;         // (d%16)/8
    const uint32_t ebyte = (uint32_t)(((mt * 16 + ks) * 64 + (code & 31) + 32 * hl) * 16
                                      + (l & 1) * 8);
    uint2 o;
    o.x = f2bf(v.x) | (f2bf(v.y) << 16);
    o.y = f2bf(v.z) | (f2bf(v.w) << 16);
    *(uint2*)(cbsw + ebyte) = o;

    #pragma unroll
    for (int m = 32; m; m >>= 1) sq += __shfl_xor(sq, m);
    if (l == 0) {
        const int rw = code & 31;
        const int h4 = (rw >> 2) & 1;
        const int r  = (rw & 3) | ((rw >> 3) << 2);
        nh_ord[mt * 32 + h4 * 16 + r] = -0.5f * sq;
    }
}

// ---- main: 1024 blocks x 256 threads; block = 64 hw rows.
// LDS xt entry E=(ks*2+half)*64+row holds x[row][ks*16+half*8 .. +7] as 8 bf16 (16 B).
// Wave w: n-tile nt=w&1 (rows nt*32..), code-half ch=w>>1 (codes ch*512..).
__global__ __launch_bounds__(256, 3) void vq_main(const float* __restrict__ x,
                                                  const float* __restrict__ cb,
                                                  const bf16x8_t* __restrict__ cbsw,
                                                  const float* __restrict__ nh_ord,
                                                  float* __restrict__ out,
                                                  float* __restrict__ loss_accum) {
    __shared__ uint32_t xt[16 * 2 * 64 * 4];   // 32 KB, B-frag order
    __shared__ float smin[2][64];
    __shared__ int   sidx[2][64];
    __shared__ float sxsq[4];
    __shared__ int   sfin[64];

    const int t     = threadIdx.x;
    const int w     = t >> 6;
    const int lane  = t & 63;
    const int n0    = blockIdx.x * 64;
    const int batch = n0 >> 10;
    const int hw0   = n0 & 1023;

    // ---- stage x -> LDS in fragment order (conflict-free b128 writes) + ||x||^2
    {
        const int col = t & 63;          // hw row within block
        const int oct = t >> 6;          // 0..3: d-octet selector
        const float* xp = x + (size_t)batch * (DIM * 1024) + hw0 + col;
        float sq = 0.f;
        #pragma unroll
        for (int i = 0; i < 8; ++i) {
            const int d0 = oct * 8 + i * 32;     // 8 consecutive d, one LDS entry
            float a[8];
            #pragma unroll
            for (int j = 0; j < 8; ++j) {
                a[j] = xp[(size_t)(d0 + j) * 1024];
                sq += a[j] * a[j];
            }
            uint4 pk;
            pk.x = f2bf(a[0]) | (f2bf(a[1]) << 16);
            pk.y = f2bf(a[2]) | (f2bf(a[3]) << 16);
            pk.z = f2bf(a[4]) | (f2bf(a[5]) << 16);
            pk.w = f2bf(a[6]) | (f2bf(a[7]) << 16);
            const int ks   = d0 >> 4;
            const int half = (d0 >> 3) & 1;
            *(uint4*)&xt[(ks * 512) + (half * 256) + col * 4] = pk;
        }
        // wave-level ||x||^2 partial (all 256 threads cover every (row,d) once)
        #pragma unroll
        for (int m = 32; m; m >>= 1) sq += __shfl_xor(sq, m);
        if (lane == 0) sxsq[w] = sq;
    }
    __syncthreads();

    // ---- K-loop: wave's 512 codes (16 m-tiles); argmax(dot - 0.5*||c||^2)
    const int nt   = w & 1;
    const int ch   = w >> 1;
    const int half = lane >> 5;
    const int col  = lane & 31;
    const uint32_t* xbase = xt + half * 256 + (nt * 32 + col) * 4;

    float best = -3.0e38f;
    int   bi = 0;
    for (int i = 0; i < 16; ++i) {
        const int mt = ch * 16 + i;

        // batch-prefetch all 16 A-frags of this m-tile (16 independent
        // global_load_dwordx4 issued before any MFMA consumes them)
        bf16x8_t apre[16];
        {
            const bf16x8_t* ap = cbsw + mt * (16 * 64) + lane;
            #pragma unroll
            for (int ks = 0; ks < 16; ++ks) apre[ks] = ap[ks * 64];
        }

        const f32x4_t* nhp = (const f32x4_t*)(nh_ord + mt * 32 + half * 16);
        const f32x4_t h0 = nhp[0], h1 = nhp[1], h2 = nhp[2], h3 = nhp[3];
        f32x16_t acc;
        #pragma unroll
        for (int r = 0; r < 4; ++r) {
            acc[r] = h0[r]; acc[4 + r] = h1[r]; acc[8 + r] = h2[r]; acc[12 + r] = h3[r];
        }
        #pragma unroll
        for (int ks = 0; ks < 16; ++ks) {
            const bf16x8_t b = *(const bf16x8_t*)(xbase + ks * 512);
            acc = __builtin_amdgcn_mfma_f32_32x32x16_bf16(apre[ks], b, acc, 0, 0, 0);
        }
        #pragma unroll
        for (int r = 0; r < 16; ++r) {
            const int code = mt * 32 + half * 4 + ((r & 3) + 8 * (r >> 2));
            if (acc[r] > best) { best = acc[r]; bi = code; }
        }
    }

    // ---- combine the two k-half lanes (same hw row, disjoint code subsets)
    {
        const float ov = __shfl_xor(best, 32);
        const int   oi = __shfl_xor(bi, 32);
        if (ov > best || (ov == best && oi < bi)) { best = ov; bi = oi; }
    }
    if (lane < 32) {
        smin[ch][nt * 32 + lane] = best;
        sidx[ch][nt * 32 + lane] = bi;
    }
    __syncthreads();

    // ---- wave 0: combine code halves per row, loss partial, publish indices
    if (w == 0) {
        float b0 = smin[0][lane]; int i0 = sidx[0][lane];
        const float b1 = smin[1][lane]; const int i1 = sidx[1][lane];
        if (b1 > b0) { b0 = b1; i0 = i1; }
        sfin[lane] = i0;
        float ls = -2.f * b0;
        #pragma unroll
        for (int m = 32; m; m >>= 1) ls += __shfl_xor(ls, m);
        if (lane == 0)
            atomicAdd(loss_accum, ls + sxsq[0] + sxsq[1] + sxsq[2] + sxsq[3]);
    }
    __syncthreads();

    // ---- epilogue: gather fp32 codebook rows, dwordx4 stores along hw
    {
        const int q  = t & 15;     // rows 4q..4q+3
        const int dg = t >> 4;     // 0..15 -> d in [dg*16, dg*16+16)
        const int c0 = sfin[4 * q + 0], c1 = sfin[4 * q + 1];
        const int c2 = sfin[4 * q + 2], c3 = sfin[4 * q + 3];
        const float* r0 = cb + c0 * DIM;
        const float* r1 = cb + c1 * DIM;
        const float* r2 = cb + c2 * DIM;
        const float* r3 = cb + c3 * DIM;
        float* ob = out + (size_t)batch * (DIM * 1024) + hw0 + 4 * q;
        #pragma unroll 4
        for (int j = 0; j < 16; ++j) {
            const int d = dg * 16 + j;
            f32x4_t v; v.x = r0[d]; v.y = r1[d]; v.z = r2[d]; v.w = r3[d];
            *(f32x4_t*)(ob + (size_t)d * 1024) = v;
        }
    }
}

// ---- finalize loss ----
__global__ void vq_final(const float* __restrict__ loss_accum, float* __restrict__ out_loss) {
    *out_loss = 1.25f * (*loss_accum) / 16777216.f;
}

extern "C" void kernel_launch(void* const* d_in, const int* in_sizes, int n_in,
                              void* d_out, int out_size, void* d_ws, size_t ws_size,
                              hipStream_t stream) {
    const float* x  = (const float*)d_in[0];   // [64,256,32,32]
    const float* cb = (const float*)d_in[1];   // [1024,256]
    float* out = (float*)d_out;                // 16777216 + 1

    char* ws = (char*)d_ws;
    float* loss_accum = (float*)ws;                        // 4 B
    char*  cbsw       = ws + 1024;                         // 512 KB, A-frag order
    float* nh_ord     = (float*)(ws + 1024 + 512 * 1024);  // 4 KB

    hipMemsetAsync(loss_accum, 0, sizeof(float), stream);
    vq_prep<<<dim3(256), dim3(256), 0, stream>>>(cb, cbsw, nh_ord);
    vq_main<<<dim3(1024), dim3(256), 0, stream>>>(x, cb, (const bf16x8_t*)cbsw, nh_ord,
                                                  out, loss_accum);
    vq_final<<<dim3(1), dim3(1), 0, stream>>>(loss_accum, out + 16777216);
}